// Round 1
// baseline (1575.475 us; speedup 1.0000x reference)
//
#include <hip/hip_runtime.h>

typedef float v2f __attribute__((ext_vector_type(2)));
typedef float v4f __attribute__((ext_vector_type(4)));

#define N_IN   131072
#define K_EMB  1024
#define D_EMB  64
#define QUANT_OFF 1
#define PERP_OFF  (1 + N_IN * D_EMB)      /* 8388609 */
#define ENC_OFF   (PERP_OFF + 1)          /* 8388610: byte offset %16==8 -> float2 stores only */

// ws layout (4-byte units):
//   [0..1023]    counts (u32)
//   [1024]       loss accumulator (f32)
//   [2048..3071] half squared norms of codes (f32)

__global__ __launch_bounds__(256) void k_prep(const float* __restrict__ emb,
                                              float* __restrict__ ws) {
  int k = blockIdx.x * 256 + threadIdx.x;  // grid=4 -> k in [0,1024)
  ((unsigned int*)ws)[k] = 0u;
  if (k == 0) ws[1024] = 0.0f;
  const float* e = emb + (size_t)k * D_EMB;
  double s = 0.0;
  #pragma unroll
  for (int d = 0; d < D_EMB; ++d) { double v = (double)e[d]; s += v * v; }
  ws[2048 + k] = (float)(0.5 * s);
}

__global__ __launch_bounds__(256, 4) void k_main(const float* __restrict__ xg,
                                                 const float* __restrict__ emb,
                                                 float* __restrict__ out,
                                                 float* __restrict__ ws) {
  __shared__ float sc_sh[256];
  __shared__ int   id_sh[256];
  __shared__ float red[256];

  const int tid  = threadIdx.x;
  const int lane = tid & 127;   // sample slot within block
  const int half = tid >> 7;    // which half of the codebook this thread scans
  const int srow = blockIdx.x * 128 + lane;

  // x fully register-resident: 16 x float4
  v4f xr[16];
  const v4f* xp = (const v4f*)(xg + (size_t)srow * D_EMB);
  #pragma unroll
  for (int j = 0; j < 16; ++j) xr[j] = xp[j];

  const float* hn = ws + 2048;
  float best = 3.4e38f;
  int   bidx = 0;
  const int k0 = half * 512;

  #pragma unroll 2
  for (int kk = 0; kk < 512; ++kk) {
    const int k = k0 + kk;
    const v4f* ep = (const v4f*)(emb + ((size_t)k << 6));  // wave-uniform address
    v4f acc;
    acc.x = 0.f; acc.y = 0.f; acc.z = 0.f; acc.w = 0.f;
    #pragma unroll
    for (int j = 0; j < 16; ++j) {
      v4f ev = ep[j];
      acc.x = fmaf(xr[j].x, ev.x, acc.x);
      acc.y = fmaf(xr[j].y, ev.y, acc.y);
      acc.z = fmaf(xr[j].z, ev.z, acc.z);
      acc.w = fmaf(xr[j].w, ev.w, acc.w);
    }
    float dot = (acc.x + acc.y) + (acc.z + acc.w);
    float sc  = hn[k] - dot;              // 0.5||e||^2 - x.e : same argmin as full distance
    if (sc < best) { best = sc; bidx = k; }   // strict < keeps first (lowest k) on ties
  }

  sc_sh[tid] = best;
  id_sh[tid] = bidx;
  __syncthreads();

  float lsum = 0.0f;
  if (tid < 128) {
    float s0 = sc_sh[tid], s1 = sc_sh[tid + 128];
    int   b0 = id_sh[tid], b1 = id_sh[tid + 128];
    int   bk = (s1 < s0) ? b1 : b0;       // tie -> half 0 (lower k), matches argmin-first
    id_sh[tid] = bk;
    atomicAdd((unsigned int*)ws + bk, 1u);
    const v4f* eb = (const v4f*)(emb + ((size_t)bk << 6));
    #pragma unroll
    for (int j = 0; j < 16; ++j) {
      v4f ev = eb[j];
      float dx;
      dx = ev.x - xr[j].x; lsum = fmaf(dx, dx, lsum);
      dx = ev.y - xr[j].y; lsum = fmaf(dx, dx, lsum);
      dx = ev.z - xr[j].z; lsum = fmaf(dx, dx, lsum);
      dx = ev.w - xr[j].w; lsum = fmaf(dx, dx, lsum);
    }
  }
  red[tid] = lsum;
  __syncthreads();
  #pragma unroll
  for (int off = 128; off > 0; off >>= 1) {
    if (tid < off) red[tid] += red[tid + off];
    __syncthreads();
  }
  if (tid == 0) atomicAdd(ws + 1024, red[0]);

  // ---- cooperative coalesced quantized write (128 rows x 64) ----
  // quantized = x + (e - x): mirrors the reference's straight-through arithmetic
  float* qblk = out + QUANT_OFF + (size_t)blockIdx.x * (128 * 64);
  const float* xblk = xg + (size_t)blockIdx.x * (128 * 64);
  #pragma unroll 1
  for (int it = 0; it < 32; ++it) {
    int f = it * 256 + tid;
    int r = f >> 6, d = f & 63;
    float ev = emb[((size_t)id_sh[r] << 6) + d];
    float xv = xblk[f];
    __builtin_nontemporal_store(xv + (ev - xv), qblk + f);
  }

  // ---- cooperative coalesced encodings write (128 rows x 1024, one-hot) ----
  v2f* eblk = (v2f*)(out + ENC_OFF) + (size_t)blockIdx.x * (128 * 512);
  #pragma unroll 1
  for (int r = 0; r < 128; ++r) {
    int hit = id_sh[r];           // broadcast LDS read
    int hc  = hit >> 1;
    v2f one; one.x = (hit & 1) ? 0.0f : 1.0f; one.y = (hit & 1) ? 1.0f : 0.0f;
    v2f zer; zer.x = 0.0f; zer.y = 0.0f;
    v2f* rowp = eblk + (size_t)r * 512;
    __builtin_nontemporal_store((hc == tid)       ? one : zer, rowp + tid);
    __builtin_nontemporal_store((hc == tid + 256) ? one : zer, rowp + tid + 256);
  }
}

__global__ __launch_bounds__(256) void k_fin(float* __restrict__ out,
                                             const float* __restrict__ ws) {
  __shared__ float red[256];
  const unsigned int* counts = (const unsigned int*)ws;
  int t = threadIdx.x;
  float s = 0.0f;
  #pragma unroll
  for (int i = 0; i < 4; ++i) {
    float p = (float)counts[t + i * 256] * (1.0f / (float)N_IN);
    s += p * __logf(p + 1e-10f);
  }
  red[t] = s;
  __syncthreads();
  #pragma unroll
  for (int off = 128; off > 0; off >>= 1) {
    if (t < off) red[t] += red[t + off];
    __syncthreads();
  }
  if (t == 0) {
    out[PERP_OFF] = __expf(-red[0]);
    out[0] = 0.25f * ws[1024] * (1.0f / (float)(N_IN * D_EMB));
  }
}

extern "C" void kernel_launch(void* const* d_in, const int* in_sizes, int n_in,
                              void* d_out, int out_size, void* d_ws, size_t ws_size,
                              hipStream_t stream) {
  (void)in_sizes; (void)n_in; (void)out_size; (void)ws_size;
  const float* x   = (const float*)d_in[0];
  const float* emb = (const float*)d_in[1];
  float* out = (float*)d_out;
  float* ws  = (float*)d_ws;

  hipLaunchKernelGGL(k_prep, dim3(4),    dim3(256), 0, stream, emb, ws);
  hipLaunchKernelGGL(k_main, dim3(1024), dim3(256), 0, stream, x, emb, out, ws);
  hipLaunchKernelGGL(k_fin,  dim3(1),    dim3(256), 0, stream, out, ws);
}

// Round 2
// 1210.786 us; speedup vs baseline: 1.3012x; 1.3012x over previous
//
#include <hip/hip_runtime.h>

typedef float v2f __attribute__((ext_vector_type(2)));
typedef float v4f __attribute__((ext_vector_type(4)));

#define N_IN   131072
#define K_EMB  1024
#define D_EMB  64
#define QUANT_OFF 1
#define PERP_OFF  (1 + N_IN * D_EMB)      /* 8388609 */
#define ENC_OFF   (PERP_OFF + 1)          /* 8388610: byte offset %16==8 -> float2 stores only */

// ws layout (4-byte units):
//   [0..1023]    counts (u32)
//   [1024]       loss accumulator (f32)
//   [2048..3071] half squared norms of codes (f32)

__global__ __launch_bounds__(256) void k_prep(const float* __restrict__ emb,
                                              float* __restrict__ ws) {
  int k = blockIdx.x * 256 + threadIdx.x;  // grid=4 -> k in [0,1024)
  ((unsigned int*)ws)[k] = 0u;
  if (k == 0) ws[1024] = 0.0f;
  const float* e = emb + (size_t)k * D_EMB;
  double s = 0.0;
  #pragma unroll
  for (int d = 0; d < D_EMB; ++d) { double v = (double)e[d]; s += v * v; }
  ws[2048 + k] = (float)(0.5 * s);
}

// One sample per thread, full 1024-code scan, x register-resident (64 VGPR),
// depth-2 software pipeline on the broadcast code-vector loads.
// __launch_bounds__(256,2): 256-VGPR budget -> compiler keeps x resident
// (R1 failure mode: (256,4) capped at 128 regs -> x rematerialized from
// global inside the loop -> latency-bound at VALUBusy=28%).
__global__ __launch_bounds__(256, 2) void k_main(const float* __restrict__ xg,
                                                 const float* __restrict__ emb,
                                                 float* __restrict__ out,
                                                 float* __restrict__ ws) {
  __shared__ int   id_sh[256];
  __shared__ float red[256];

  const int tid = threadIdx.x;
  const size_t row = (size_t)blockIdx.x * 256 + tid;

  // x fully register-resident: 16 x float4
  v4f xr[16];
  const v4f* xp = (const v4f*)(xg + row * D_EMB);
  #pragma unroll
  for (int j = 0; j < 16; ++j) xr[j] = xp[j];

  const float* hn = ws + 2048;
  const v4f* eb = (const v4f*)emb;

  float best = 3.4e38f;
  int   bidx = 0;

  // pipeline: cva holds code k, cvb holds code k+1 (loaded one step ahead)
  v4f cva[16], cvb[16];
  float ha, hb;
  #pragma unroll
  for (int j = 0; j < 16; ++j) cva[j] = eb[j];
  ha = hn[0];

  #pragma unroll 1
  for (int k = 0; k < 1024; k += 2) {
    // issue loads for code k+1 (consumed after cva's 64 FMAs)
    {
      const v4f* p = eb + ((size_t)(k + 1) << 4);
      #pragma unroll
      for (int j = 0; j < 16; ++j) cvb[j] = p[j];
      hb = hn[k + 1];
    }
    // score code k with cva
    {
      v4f acc; acc.x = 0.f; acc.y = 0.f; acc.z = 0.f; acc.w = 0.f;
      #pragma unroll
      for (int j = 0; j < 16; ++j) {
        acc.x = fmaf(xr[j].x, cva[j].x, acc.x);
        acc.y = fmaf(xr[j].y, cva[j].y, acc.y);
        acc.z = fmaf(xr[j].z, cva[j].z, acc.z);
        acc.w = fmaf(xr[j].w, cva[j].w, acc.w);
      }
      float dot = (acc.x + acc.y) + (acc.z + acc.w);
      float sc  = ha - dot;                    // 0.5||e||^2 - x.e
      bool c = sc < best;                      // strict <: first (lowest k) wins ties
      best = c ? sc : best;
      bidx = c ? k : bidx;
    }
    // issue loads for code k+2 (wrap-masked on the final iteration; unscored)
    {
      const v4f* p = eb + ((size_t)((k + 2) & 1023) << 4);
      #pragma unroll
      for (int j = 0; j < 16; ++j) cva[j] = p[j];
      ha = hn[(k + 2) & 1023];
    }
    // score code k+1 with cvb
    {
      v4f acc; acc.x = 0.f; acc.y = 0.f; acc.z = 0.f; acc.w = 0.f;
      #pragma unroll
      for (int j = 0; j < 16; ++j) {
        acc.x = fmaf(xr[j].x, cvb[j].x, acc.x);
        acc.y = fmaf(xr[j].y, cvb[j].y, acc.y);
        acc.z = fmaf(xr[j].z, cvb[j].z, acc.z);
        acc.w = fmaf(xr[j].w, cvb[j].w, acc.w);
      }
      float dot = (acc.x + acc.y) + (acc.z + acc.w);
      float sc  = hb - dot;
      bool c = sc < best;
      best = c ? sc : best;
      bidx = c ? (k + 1) : bidx;
    }
  }

  id_sh[tid] = bidx;
  atomicAdd((unsigned int*)ws + bidx, 1u);

  // commitment-loss partial: ||e_best - x||^2 for this thread's own sample
  float lsum = 0.0f;
  {
    const v4f* ebest = eb + ((size_t)bidx << 4);
    #pragma unroll
    for (int j = 0; j < 16; ++j) {
      v4f ev = ebest[j];
      float dx;
      dx = ev.x - xr[j].x; lsum = fmaf(dx, dx, lsum);
      dx = ev.y - xr[j].y; lsum = fmaf(dx, dx, lsum);
      dx = ev.z - xr[j].z; lsum = fmaf(dx, dx, lsum);
      dx = ev.w - xr[j].w; lsum = fmaf(dx, dx, lsum);
    }
  }
  red[tid] = lsum;
  __syncthreads();
  #pragma unroll
  for (int off = 128; off > 0; off >>= 1) {
    if (tid < off) red[tid] += red[tid + off];
    __syncthreads();
  }
  if (tid == 0) atomicAdd(ws + 1024, red[0]);

  // ---- cooperative coalesced quantized write (256 rows x 64) ----
  // quantized = x + (e - x): mirrors the reference arithmetic exactly (fp32)
  float* qblk = out + QUANT_OFF + (size_t)blockIdx.x * (256 * 64);
  const float* xblk = xg + (size_t)blockIdx.x * (256 * 64);
  #pragma unroll 1
  for (int it = 0; it < 64; ++it) {
    int f = it * 256 + tid;
    int r = f >> 6, d = f & 63;
    float ev = emb[((size_t)id_sh[r] << 6) + d];
    float xv = xblk[f];
    __builtin_nontemporal_store(xv + (ev - xv), qblk + f);
  }

  // ---- cooperative coalesced encodings write (256 rows x 1024, one-hot) ----
  v2f* eblk = (v2f*)(out + ENC_OFF) + (size_t)blockIdx.x * (256 * 512);
  #pragma unroll 1
  for (int r = 0; r < 256; ++r) {
    int hit = id_sh[r];           // broadcast LDS read
    int hc  = hit >> 1;
    v2f one; one.x = (hit & 1) ? 0.0f : 1.0f; one.y = (hit & 1) ? 1.0f : 0.0f;
    v2f zer; zer.x = 0.0f; zer.y = 0.0f;
    v2f* rowp = eblk + (size_t)r * 512;
    __builtin_nontemporal_store((hc == tid)       ? one : zer, rowp + tid);
    __builtin_nontemporal_store((hc == tid + 256) ? one : zer, rowp + tid + 256);
  }
}

__global__ __launch_bounds__(256) void k_fin(float* __restrict__ out,
                                             const float* __restrict__ ws) {
  __shared__ float red[256];
  const unsigned int* counts = (const unsigned int*)ws;
  int t = threadIdx.x;
  float s = 0.0f;
  #pragma unroll
  for (int i = 0; i < 4; ++i) {
    float p = (float)counts[t + i * 256] * (1.0f / (float)N_IN);
    s += p * __logf(p + 1e-10f);
  }
  red[t] = s;
  __syncthreads();
  #pragma unroll
  for (int off = 128; off > 0; off >>= 1) {
    if (t < off) red[t] += red[t + off];
    __syncthreads();
  }
  if (t == 0) {
    out[PERP_OFF] = __expf(-red[0]);
    out[0] = 0.25f * ws[1024] * (1.0f / (float)(N_IN * D_EMB));
  }
}

extern "C" void kernel_launch(void* const* d_in, const int* in_sizes, int n_in,
                              void* d_out, int out_size, void* d_ws, size_t ws_size,
                              hipStream_t stream) {
  (void)in_sizes; (void)n_in; (void)out_size; (void)ws_size;
  const float* x   = (const float*)d_in[0];
  const float* emb = (const float*)d_in[1];
  float* out = (float*)d_out;
  float* ws  = (float*)d_ws;

  hipLaunchKernelGGL(k_prep, dim3(4),   dim3(256), 0, stream, emb, ws);
  hipLaunchKernelGGL(k_main, dim3(512), dim3(256), 0, stream, x, emb, out, ws);
  hipLaunchKernelGGL(k_fin,  dim3(1),   dim3(256), 0, stream, out, ws);
}